// Round 17
// baseline (62.345 us; speedup 1.0000x reference)
//
#include <hip/hip_runtime.h>
#include <math.h>

#define HS 64
#define WS 208
#define HF 128
#define WF 416
#define NS (HS * WS)   // 13312
#define KH 20
#define KS 41
#define KK (KS * KS)   // 1681
#define UCOL 48        // octet column-union width (7 + 41)
#define GEL (KS * UCOL) // 1968 elements per octet union
#define NIT 31         // 30*64 + 48
#define NWAVE (64 * 26) // 1664 octets
#define LOG2E 1.442695040888963f

// align_corners grid: f32 coords exactly as _resize_ac (arange(f32) * (f32(in-1)/f32(out-1))).
__device__ __forceinline__ void ac_idx(int o, int inN, float sc, int& i0, int& i1, float& w) {
#pragma clang fp contract(off)
    float s = (float)o * sc;
    float f = floorf(s);
    i0 = (int)f;
    i1 = min(i0 + 1, inN - 1);
    w = s - f;
}

// k_down: bit-faithful f32 resize of R -> ray4 (padded float4 triples) and of X ->
// normalized dir4; thread 0 also computes the f32 temperature.
__global__ void k_down(const float* __restrict__ R, const float* __restrict__ X,
                       const int* __restrict__ prog,
                       float4* __restrict__ ray4, float4* __restrict__ dir4,
                       float* __restrict__ tbuf) {
#pragma clang fp contract(off)
    int n = blockIdx.x * blockDim.x + threadIdx.x;
    if (n >= NS) return;
    if (n == 0) {
        double T64 = fmax(1e-8, 1e-4 / exp(0.1 * (double)prog[0]));
        tbuf[0] = (float)T64;   // same bits as np.float32(max(1e-8, 1e-4/exp(...)))
    }
    int y = n / WS, x = n - y * WS;
    int y0, y1, x0, x1; float wy, wx;
    ac_idx(y, HF, 127.0f / 63.0f, y0, y1, wy);
    ac_idx(x, WF, 415.0f / 207.0f, x0, x1, wx);
    float omwy = 1.0f - wy, omwx = 1.0f - wx;
    float r[3], d[3];
#pragma unroll
    for (int c = 0; c < 3; ++c) {
        const float* p = R + c * (HF * WF);
        float v00 = p[y0 * WF + x0], v10 = p[y1 * WF + x0];
        float v01 = p[y0 * WF + x1], v11 = p[y1 * WF + x1];
        float a0 = v00 * omwy; float b0 = v10 * wy; float t0 = a0 + b0;
        float a1 = v01 * omwy; float b1 = v11 * wy; float t1 = a1 + b1;
        float c0 = t0 * omwx; float c1 = t1 * wx;
        r[c] = c0 + c1;
        const float* q = X + c * (HF * WF);
        float u00 = q[y0 * WF + x0], u10 = q[y1 * WF + x0];
        float u01 = q[y0 * WF + x1], u11 = q[y1 * WF + x1];
        float e0 = u00 * omwy; float f0 = u10 * wy; float s0 = e0 + f0;
        float e1 = u01 * omwy; float f1 = u11 * wy; float s1 = e1 + f1;
        float g0 = s0 * omwx; float g1 = s1 * wx;
        d[c] = g0 + g1;
    }
    float q0 = d[0] * d[0]; float q1 = d[1] * d[1]; float q2 = d[2] * d[2];
    float ssq = (q0 + q1) + q2;
    float nrm = (float)sqrt((double)ssq);   // correctly-rounded f32 sqrt
    ray4[n] = make_float4(r[0], r[1], r[2], 0.0f);
    dir4[n] = make_float4(d[0] / nrm, d[1] / nrm, d[2] / nrm, 0.0f);
}

// One WAVE per 8-pixel horizontal octet. Lanes sweep the 41x48 column-union once;
// each loaded float4 feeds 8 register-held direction dots (~104 VALU per load).
// No LDS, no barriers. Pass 2 ffs-walks superset-flagged survivors (exact IEEE
// div + exp2, same semantics as all prior passing rounds).
__global__ __launch_bounds__(128) void k_main(const float4* __restrict__ ray4,
                                              const float4* __restrict__ dir4,
                                              const float* __restrict__ tbuf,
                                              float* __restrict__ xn, float* __restrict__ yn) {
#pragma clang fp contract(off)
    int tid = (int)threadIdx.x;
    int lane = tid & 63;
    int gw = (int)blockIdx.x * 2 + (tid >> 6);    // wave id 0..1663
    int row = (gw * 2521) >> 16;                  // exact floor(gw/26) for gw<1664
    int grp = gw - row * 26;
    int w0 = grp * 8;
    int srow = min(max(row - KH, 0), HS - 1 - 2 * KH);
    int scol0 = min(max(w0 - KH, 0), WS - 1 - 2 * KH);
    float Tf = tbuf[0];

    float d0[8], d1[8], d2[8];
    int dJ[8];
#pragma unroll
    for (int i = 0; i < 8; ++i) {
        float4 dv = dir4[row * WS + w0 + i];
        d0[i] = dv.x; d1[i] = dv.y; d2[i] = dv.z;
        dJ[i] = min(max(w0 + i - KH, 0), WS - 1 - 2 * KH) - scol0;   // 0..7
    }
    int base = srow * WS + scol0;

    // ---- pass 1: raw logits, bit-exact ((p0+p1)+p2); running max + superset flag ----
    float m[8];
    unsigned msk[8];
#pragma unroll
    for (int i = 0; i < 8; ++i) { m[i] = -INFINITY; msk[i] = 0u; }
#pragma unroll
    for (int it = 0; it < NIT; ++it) {
        if (it < NIT - 1 || lane < GEL - 64 * (NIT - 1)) {
            int e = lane + 64 * it;
            int rho = (e * 683) >> 15;        // exact floor(e/48) for e<2048
            int j = e - rho * UCOL;
            float4 v = ray4[base + rho * WS + j];   // OOB(<=+7) lands in dir4: masked
#pragma unroll
            for (int i = 0; i < 8; ++i) {
                float p0 = d0[i] * v.x; float p1 = d1[i] * v.y; float p2 = d2[i] * v.z;
                float l = (p0 + p1) + p2;
                int c = j - dJ[i];
                bool valid = (unsigned)c <= 40u;
                float lv = valid ? l : -INFINITY;
                bool f = (lv + 0.005f) > m[i];      // superset of {l > m_final-0.004}
                msk[i] |= f ? (1u << it) : 0u;
                m[i] = fmaxf(m[i], lv);
            }
        }
    }
    // wave butterfly max -> all lanes hold each pixel's window max
#pragma unroll
    for (int s = 1; s < 64; s <<= 1) {
#pragma unroll
        for (int i = 0; i < 8; ++i) m[i] = fmaxf(m[i], __shfl_xor(m[i], s));
    }

    // ---- pass 2: revisit flagged elements; exact IEEE div + exp2 ----
    float se[8], sr[8], sc[8];
#pragma unroll
    for (int i = 0; i < 8; ++i) { se[i] = 0.f; sr[i] = 0.f; sc[i] = 0.f; }
#pragma unroll
    for (int i = 0; i < 8; ++i) {
        unsigned w8 = msk[i];
        if (__ballot(w8 != 0u)) {
            float th = m[i] - 0.004f;   // below: z-zm < -108 -> f32 weight exactly 0
            float zm = m[i] / Tf;       // monotone div: == ref's max-of-(l/T)
            while (w8) {
                int it = __ffs(w8) - 1;
                w8 &= w8 - 1;
                int e = lane + (it << 6);
                int rho = (e * 683) >> 15;
                int j = e - rho * UCOL;
                float4 v = ray4[base + rho * WS + j];
                float p0 = d0[i] * v.x; float p1 = d1[i] * v.y; float p2 = d2[i] * v.z;
                float l = (p0 + p1) + p2;    // flagged => was valid (in-window)
                if (l > th) {
                    float z = l / Tf;        // bit-identical to ref's logits/T
                    float e2 = __builtin_amdgcn_exp2f((z - zm) * LOG2E);
                    se[i] += e2;
                    sr[i] += e2 * (float)(srow + rho);
                    sc[i] += e2 * (float)(scol0 + j);
                }
            }
        }
    }
    // butterfly sum; lane 0 owns statically-indexed totals for all 8 px
#pragma unroll
    for (int s = 1; s < 64; s <<= 1) {
#pragma unroll
        for (int i = 0; i < 8; ++i) {
            se[i] += __shfl_xor(se[i], s);
            sr[i] += __shfl_xor(sr[i], s);
            sc[i] += __shfl_xor(sc[i], s);
        }
    }
    if (lane == 0) {
#pragma unroll
        for (int i = 0; i < 8; ++i) {
            int pix = row * WS + w0 + i;
            double ix = (double)sr[i] / (double)se[i];
            double iy = (double)sc[i] / (double)se[i];
            xn[pix] = (float)(2.0 * ix / (double)(HS - 1) - 1.0);
            yn[pix] = (float)(2.0 * iy / (double)(WS - 1) - 1.0);
        }
    }
}

// Bilinear upsample (align_corners) of (Yn, Xn) to full res, interleaved channels.
__global__ void k_up(const float* __restrict__ xn, const float* __restrict__ yn,
                     float* __restrict__ out) {
#pragma clang fp contract(off)
    int i = blockIdx.x * blockDim.x + threadIdx.x;
    if (i >= HF * WF) return;
    int hh = i / WF, ww = i - hh * WF;
    int y0, y1, x0, x1; float wy, wx;
    ac_idx(hh, HS, 63.0f / 127.0f, y0, y1, wy);
    ac_idx(ww, WS, 207.0f / 415.0f, x0, x1, wx);
    float omwy = 1.0f - wy, omwx = 1.0f - wx;
    float a0, b0, t0, t1;
    a0 = xn[y0 * WS + x0] * omwy; b0 = xn[y1 * WS + x0] * wy; t0 = a0 + b0;
    a0 = xn[y0 * WS + x1] * omwy; b0 = xn[y1 * WS + x1] * wy; t1 = a0 + b0;
    float bx = t0 * omwx + t1 * wx;     // Xn upsampled
    a0 = yn[y0 * WS + x0] * omwy; b0 = yn[y1 * WS + x0] * wy; t0 = a0 + b0;
    a0 = yn[y0 * WS + x1] * omwy; b0 = yn[y1 * WS + x1] * wy; t1 = a0 + b0;
    float ay = t0 * omwx + t1 * wx;     // Yn upsampled
    out[2 * i]     = ay;
    out[2 * i + 1] = bx;
}

extern "C" void kernel_launch(void* const* d_in, const int* in_sizes, int n_in,
                              void* d_out, int out_size, void* d_ws, size_t ws_size,
                              hipStream_t stream) {
    const float* R = (const float*)d_in[0];
    const float* X = (const float*)d_in[1];
    const int* prog = (const int*)d_in[2];
    float4* ray4 = (float4*)d_ws;            // NS float4
    float4* dir4 = ray4 + NS;                // NS float4 (also OOB landing zone)
    float* xn   = (float*)(dir4 + NS);       // NS
    float* yn   = xn + NS;                   // NS
    float* tbuf = yn + NS;                   // 1
    float* out  = (float*)d_out;

    k_down<<<(NS + 255) / 256, 256, 0, stream>>>(R, X, prog, ray4, dir4, tbuf);
    k_main<<<NWAVE / 2, 128, 0, stream>>>(ray4, dir4, tbuf, xn, yn);  // wave per octet
    k_up<<<(HF * WF + 255) / 256, 256, 0, stream>>>(xn, yn, out);
}

// Round 18
// 36.849 us; speedup vs baseline: 1.6919x; 1.6919x over previous
//
#include <hip/hip_runtime.h>
#include <math.h>

#define HS 64
#define WS 208
#define HF 128
#define WF 416
#define NS (HS * WS)   // 13312
#define KH 20
#define KS 41
#define KK (KS * KS)   // 1681
#define TCOL 48        // staged octet window cols (7 + 41)
#define PITCH 49       // float4 row pitch in LDS
#define TEL (KS * TCOL) // 41*48 = 1968 staged elements
#define NBLK (HS * 26) // 1664 octet blocks
#define LOG2E 1.442695040888963f

// align_corners grid: f32 coords exactly as _resize_ac (arange(f32) * (f32(in-1)/f32(out-1))).
__device__ __forceinline__ void ac_idx(int o, int inN, float sc, int& i0, int& i1, float& w) {
#pragma clang fp contract(off)
    float s = (float)o * sc;
    float f = floorf(s);
    i0 = (int)f;
    i1 = min(i0 + 1, inN - 1);
    w = s - f;
}

// k_down: bit-faithful f32 resize of R -> ray4 (padded float4 triples) and of X ->
// normalized dir4; thread 0 also computes the f32 temperature.
__global__ void k_down(const float* __restrict__ R, const float* __restrict__ X,
                       const int* __restrict__ prog,
                       float4* __restrict__ ray4, float4* __restrict__ dir4,
                       float* __restrict__ tbuf) {
#pragma clang fp contract(off)
    int n = blockIdx.x * blockDim.x + threadIdx.x;
    if (n >= NS) return;
    if (n == 0) {
        double T64 = fmax(1e-8, 1e-4 / exp(0.1 * (double)prog[0]));
        tbuf[0] = (float)T64;   // same bits as np.float32(max(1e-8, 1e-4/exp(...)))
    }
    int y = n / WS, x = n - y * WS;
    int y0, y1, x0, x1; float wy, wx;
    ac_idx(y, HF, 127.0f / 63.0f, y0, y1, wy);
    ac_idx(x, WF, 415.0f / 207.0f, x0, x1, wx);
    float omwy = 1.0f - wy, omwx = 1.0f - wx;
    float r[3], d[3];
#pragma unroll
    for (int c = 0; c < 3; ++c) {
        const float* p = R + c * (HF * WF);
        float v00 = p[y0 * WF + x0], v10 = p[y1 * WF + x0];
        float v01 = p[y0 * WF + x1], v11 = p[y1 * WF + x1];
        float a0 = v00 * omwy; float b0 = v10 * wy; float t0 = a0 + b0;
        float a1 = v01 * omwy; float b1 = v11 * wy; float t1 = a1 + b1;
        float c0 = t0 * omwx; float c1 = t1 * wx;
        r[c] = c0 + c1;
        const float* q = X + c * (HF * WF);
        float u00 = q[y0 * WF + x0], u10 = q[y1 * WF + x0];
        float u01 = q[y0 * WF + x1], u11 = q[y1 * WF + x1];
        float e0 = u00 * omwy; float f0 = u10 * wy; float s0 = e0 + f0;
        float e1 = u01 * omwy; float f1 = u11 * wy; float s1 = e1 + f1;
        float g0 = s0 * omwx; float g1 = s1 * wx;
        d[c] = g0 + g1;
    }
    float q0 = d[0] * d[0]; float q1 = d[1] * d[1]; float q2 = d[2] * d[2];
    float ssq = (q0 + q1) + q2;
    float nrm = (float)sqrt((double)ssq);   // correctly-rounded f32 sqrt
    ray4[n] = make_float4(r[0], r[1], r[2], 0.0f);
    dir4[n] = make_float4(d[0] / nrm, d[1] / nrm, d[2] / nrm, 0.0f);
}

// k_oct: one block (512 thr, 8 waves) per 8-pixel octet; stage the 41x48 ray4
// window into LDS (coalesced), then ONE WAVE PER PIXEL does the R5-proven
// 27-iteration register sweep (lg[27], carry-chain addr) from LDS, shuffle-max,
// and register-only ballot-skip pass 2. One barrier, no cross-wave reductions.
__global__ __launch_bounds__(512) void k_oct(const float4* __restrict__ ray4,
                                             const float4* __restrict__ dir4,
                                             const float* __restrict__ tbuf,
                                             float* __restrict__ xn,
                                             float* __restrict__ yn) {
#pragma clang fp contract(off)
    __shared__ float4 tile[KS * PITCH];    // 41 rows x pitch 49
    int t = (int)threadIdx.x;
    int lane = t & 63;
    int wv = t >> 6;                       // 0..7: pixel within octet
    int blk = (int)blockIdx.x;
    int row = (blk * 2521) >> 16;          // exact floor(blk/26) for blk<1664
    int grp = blk - row * 26;
    int w0 = grp * 8;
    int srow = min(max(row - KH, 0), HS - 1 - 2 * KH);
    int scol0 = min(max(w0 - KH, 0), WS - 1 - 2 * KH);

    // ---- stage: 1968 float4, coalesced from precomputed ray4 ----
    int base = srow * WS + scol0;
#pragma unroll
    for (int s = 0; s < 4; ++s) {
        int e = t + 512 * s;
        if (e < TEL) {
            int i = (e * 683) >> 15;       // exact floor(e/48) for e<2048
            int j = e - i * TCOL;
            tile[i * PITCH + j] = ray4[base + i * WS + j];  // <= NS+6: padded
        }
    }
    __syncthreads();

    // ---- per-wave (per-pixel) setup ----
    int wpx = w0 + wv;
    int scolp = min(max(wpx - KH, 0), WS - 1 - 2 * KH);
    int dJ = scolp - scol0;                // 0..7
    float4 dv = dir4[row * WS + wpx];
    float d0 = dv.x, d1 = dv.y, d2 = dv.z;
    float Tf = tbuf[0];

    int k1i = (lane * 25) >> 10;           // exact floor(lane/41) for lane<64
    int k2i = lane - k1i * KS;
    int loff = k1i * PITCH + dJ + k2i;
    int colk = k2i;

    // ---- pass 1: 27-iter register sweep, bit-exact ((p0+p1)+p2), running max ----
    float lg[27];
    float m = -INFINITY;
#pragma unroll
    for (int j = 0; j < 26; ++j) {
        float4 v = tile[loff];
        float p0 = d0 * v.x; float p1 = d1 * v.y; float p2 = d2 * v.z;
        float l = (p0 + p1) + p2;
        lg[j] = l;
        m = fmaxf(m, l);
        int cn = colk + 23;                // k += 64 = 1*41 + 23
        bool cr = cn >= KS;
        colk = cr ? cn - KS : cn;
        loff += cr ? (2 * PITCH - 18) : (PITCH + 23);
    }
    {   // j=26: k = lane + 1664, live iff lane < 17
        float l = -INFINITY;
        if (lane < KK - 64 * 26) {
            float4 v = tile[loff];
            float p0 = d0 * v.x; float p1 = d1 * v.y; float p2 = d2 * v.z;
            l = (p0 + p1) + p2;
        }
        lg[26] = l;
        m = fmaxf(m, l);
    }
#pragma unroll
    for (int s = 1; s < 64; s <<= 1) m = fmaxf(m, __shfl_xor(m, s));

    float zm = m / Tf;                     // monotone div: == ref's max-of-(l/T)
    float thresh = m - 0.004f;             // below: z-zm < -108 -> f32 weight exactly 0

    // ---- pass 2: register-only ballot-skip; exact IEEE div + exp2 ----
    float se = 0.f, sr = 0.f, sc = 0.f;
    int c1 = k1i, c2 = k2i;
#pragma unroll
    for (int j = 0; j < 27; ++j) {
        bool a = lg[j] > thresh;           // dead lanes hold -INF -> false
        if (__ballot(a)) {
            float z = lg[j] / Tf;          // bit-identical to ref's logits/T
            float arg = (z - zm) * LOG2E;
            float e = a ? __builtin_amdgcn_exp2f(arg) : 0.0f;
            se += e;
            sr += e * (float)(srow + c1);
            sc += e * (float)(scolp + c2);
        }
        int cn = c2 + 23;
        bool cr = cn >= KS;
        c2 = cr ? cn - KS : cn;
        c1 += cr ? 2 : 1;
    }
#pragma unroll
    for (int s = 1; s < 64; s <<= 1) {
        se += __shfl_xor(se, s);
        sr += __shfl_xor(sr, s);
        sc += __shfl_xor(sc, s);
    }
    if (lane == 0) {
        int pix = row * WS + wpx;
        double ix = (double)sr / (double)se, iy = (double)sc / (double)se;
        xn[pix] = (float)(2.0 * ix / (double)(HS - 1) - 1.0);
        yn[pix] = (float)(2.0 * iy / (double)(WS - 1) - 1.0);
    }
}

// Bilinear upsample (align_corners) of (Yn, Xn) to full res, interleaved channels.
__global__ void k_up(const float* __restrict__ xn, const float* __restrict__ yn,
                     float* __restrict__ out) {
#pragma clang fp contract(off)
    int i = blockIdx.x * blockDim.x + threadIdx.x;
    if (i >= HF * WF) return;
    int hh = i / WF, ww = i - hh * WF;
    int y0, y1, x0, x1; float wy, wx;
    ac_idx(hh, HS, 63.0f / 127.0f, y0, y1, wy);
    ac_idx(ww, WS, 207.0f / 415.0f, x0, x1, wx);
    float omwy = 1.0f - wy, omwx = 1.0f - wx;
    float a0, b0, t0, t1;
    a0 = xn[y0 * WS + x0] * omwy; b0 = xn[y1 * WS + x0] * wy; t0 = a0 + b0;
    a0 = xn[y0 * WS + x1] * omwy; b0 = xn[y1 * WS + x1] * wy; t1 = a0 + b0;
    float bx = t0 * omwx + t1 * wx;     // Xn upsampled
    a0 = yn[y0 * WS + x0] * omwy; b0 = yn[y1 * WS + x0] * wy; t0 = a0 + b0;
    a0 = yn[y0 * WS + x1] * omwy; b0 = yn[y1 * WS + x1] * wy; t1 = a0 + b0;
    float ay = t0 * omwx + t1 * wx;     // Yn upsampled
    out[2 * i]     = ay;
    out[2 * i + 1] = bx;
}

extern "C" void kernel_launch(void* const* d_in, const int* in_sizes, int n_in,
                              void* d_out, int out_size, void* d_ws, size_t ws_size,
                              hipStream_t stream) {
    const float* R = (const float*)d_in[0];
    const float* X = (const float*)d_in[1];
    const int* prog = (const int*)d_in[2];
    float4* ray4 = (float4*)d_ws;            // NS + 8 float4 (8-slot OOB pad)
    float4* dir4 = ray4 + NS + 8;            // NS float4
    float* xn   = (float*)(dir4 + NS);       // NS
    float* yn   = xn + NS;                   // NS
    float* tbuf = yn + NS;                   // 1
    float* out  = (float*)d_out;

    k_down<<<(NS + 255) / 256, 256, 0, stream>>>(R, X, prog, ray4, dir4, tbuf);
    k_oct<<<NBLK, 512, 0, stream>>>(ray4, dir4, tbuf, xn, yn);   // block per octet
    k_up<<<(HF * WF + 255) / 256, 256, 0, stream>>>(xn, yn, out);
}